// Round 1
// baseline (630.581 us; speedup 1.0000x reference)
//
#include <hip/hip_runtime.h>

// Problem constants (B=2,H=16,S=2048,D=128 — fixed by the reference).
#define S 2048
#define D 128
#define BH 32
#define ROWS (BH * S)  // 65536 rows per tensor

typedef __bf16 bf16x8 __attribute__((ext_vector_type(8)));
typedef float f32x4 __attribute__((ext_vector_type(4)));
typedef __attribute__((address_space(1))) unsigned int GU;
typedef __attribute__((address_space(3))) unsigned int LU;

__device__ __forceinline__ unsigned short f2bf(float f) {
  // round-to-nearest-even fp32 -> bf16 (finite inputs only)
  unsigned u = __float_as_uint(f);
  u += 0x7fffu + ((u >> 16) & 1u);
  return (unsigned short)(u >> 16);
}

__device__ __forceinline__ void ld_g2l16(const unsigned short* g, unsigned short* l) {
  // async 16B global->LDS; LDS dest must be wave-uniform base + lane*16
  __builtin_amdgcn_global_load_lds((const GU*)g, (LU*)l, 16, 0, 0);
}

// ---- Pass 1: L2-normalize each 128-elem row, emit bf16 -------------------
// One wave per row (64 lanes x float2), butterfly shuffle reduce.
__global__ __launch_bounds__(256) void normalize_rows(
    const float* __restrict__ x, unsigned short* __restrict__ y) {
  const int wave = threadIdx.x >> 6;
  const int lane = threadIdx.x & 63;
  const int row = (blockIdx.x << 2) + wave;
  const float2 v = ((const float2*)(x + (size_t)row * D))[lane];
  float ss = v.x * v.x + v.y * v.y;
#pragma unroll
  for (int m = 32; m; m >>= 1) ss += __shfl_xor(ss, m, 64);
  const float scale = 1.0f / fmaxf(sqrtf(ss), 1e-12f);
  const unsigned lo = f2bf(v.x * scale);
  const unsigned hi = f2bf(v.y * scale);
  ((unsigned int*)(y + (size_t)row * D))[lane] = lo | (hi << 16);
}

// ---- Pass 2: C = exp(clamp((Qn·Knᵀ)/temp)) + 1e-6 ------------------------
// 128x128 output tile per block; K=D=128 => tile is contiguous 32KB in
// global, staged with global_load_lds dwordx4. K-chunk XOR swizzle applied
// on the GLOBAL side so LDS b128 fragment reads are 2-way/bank (free).
__global__ __launch_bounds__(256, 2) void qk_exp_kernel(
    const unsigned short* __restrict__ Qn, const unsigned short* __restrict__ Kn,
    const float* __restrict__ logt, float* __restrict__ out) {
  __shared__ __align__(16) unsigned short lQ[128 * 128];
  __shared__ __align__(16) unsigned short lK[128 * 128];
  const int tid = threadIdx.x;
  const int nt_ = blockIdx.x, mt_ = blockIdx.y, bh = blockIdx.z;
  const unsigned short* Qb = Qn + ((size_t)bh * S + (size_t)mt_ * 128) * D;
  const unsigned short* Kb = Kn + ((size_t)bh * S + (size_t)nt_ * 128) * D;

#pragma unroll
  for (int it = 0; it < 8; ++it) {
    const int L = (it << 8) + tid;             // 16B-chunk index in LDS
    const int r = L >> 4, c = L & 15;          // row (256B), chunk-in-row
    const int g = (r << 4) + (c ^ (r & 15));   // swizzled global chunk
    ld_g2l16(Qb + (g << 3), lQ + (L << 3));
    ld_g2l16(Kb + (g << 3), lK + (L << 3));
  }
  __syncthreads();  // drains vmcnt(0) -> staging complete

  const int lane = tid & 63, wave = tid >> 6;
  const int wr = (wave >> 1) << 6;  // wave quadrant row origin
  const int wc = (wave & 1) << 6;   // wave quadrant col origin
  const int lm = lane & 15, kq = lane >> 4;

  f32x4 acc[4][4] = {};
#pragma unroll
  for (int ks = 0; ks < 4; ++ks) {
    const int kc = (ks << 2) + kq;       // 16B k-chunk (0..15)
    const int sw = (kc ^ lm) << 3;       // swizzled k-offset in elements
    bf16x8 a[4], b[4];
#pragma unroll
    for (int mt = 0; mt < 4; ++mt)
      a[mt] = *(const bf16x8*)(lQ + (wr + (mt << 4) + lm) * D + sw);
#pragma unroll
    for (int nt = 0; nt < 4; ++nt)
      b[nt] = *(const bf16x8*)(lK + (wc + (nt << 4) + lm) * D + sw);
#pragma unroll
    for (int mt = 0; mt < 4; ++mt)
#pragma unroll
      for (int nt = 0; nt < 4; ++nt)
        acc[mt][nt] =
            __builtin_amdgcn_mfma_f32_16x16x32_bf16(a[mt], b[nt], acc[mt][nt], 0, 0, 0);
  }

  float temp = __expf(logt[0]);
  temp = fminf(fmaxf(temp, 0.05f), 100.0f);
  const float invt = 1.0f / temp;

  float* Cb = out + ((size_t)bh << 22);  // bh * S * S
  const int rb = (mt_ << 7) + wr + (kq << 2);
  const int cb = (nt_ << 7) + wc + lm;
#pragma unroll
  for (int mt = 0; mt < 4; ++mt) {
#pragma unroll
    for (int reg = 0; reg < 4; ++reg) {
      const int row = rb + (mt << 4) + reg;  // C/D: row = (lane>>4)*4+reg
      float* rp = Cb + (size_t)row * S + cb; //      col = lane&15
#pragma unroll
      for (int nt = 0; nt < 4; ++nt) {
        float s = acc[mt][nt][reg] * invt;
        s = fminf(fmaxf(s, -100.0f), 100.0f);
        rp[nt << 4] = __expf(s) + 1e-6f;
      }
    }
  }
}

extern "C" void kernel_launch(void* const* d_in, const int* in_sizes, int n_in,
                              void* d_out, int out_size, void* d_ws, size_t ws_size,
                              hipStream_t stream) {
  const float* q = (const float*)d_in[0];
  const float* k = (const float*)d_in[1];
  const float* lt = (const float*)d_in[2];
  float* out = (float*)d_out;
  unsigned short* qn = (unsigned short*)d_ws;               // 16.78 MB
  unsigned short* kn = qn + (size_t)ROWS * D;               // 16.78 MB
  normalize_rows<<<ROWS / 4, 256, 0, stream>>>(q, qn);
  normalize_rows<<<ROWS / 4, 256, 0, stream>>>(k, kn);
  dim3 grid(S / 128, S / 128, BH);
  qk_exp_kernel<<<grid, 256, 0, stream>>>(qn, kn, lt, out);
}